// Round 6
// baseline (233.138 us; speedup 1.0000x reference)
//
#include <hip/hip_runtime.h>

#define B_   2
#define C_   256
#define N_   4096
#define H_   8
#define HD_  32
#define G_   8
#define CPG_ 32

typedef short short8 __attribute__((ext_vector_type(8)));
typedef short s4v    __attribute__((ext_vector_type(4)));
typedef float f32x4  __attribute__((ext_vector_type(4)));
typedef float f4     __attribute__((ext_vector_type(4)));

__device__ __forceinline__ float b2f(short s) {
    return __uint_as_float(((unsigned)(unsigned short)s) << 16);
}
__device__ __forceinline__ short f2b(float f) {
    unsigned u = __float_as_uint(f);
    unsigned r = (u + 0x7FFF + ((u >> 16) & 1)) >> 16;  // RNE
    return (short)r;
}

// ---------------- GN stats stage 1: 1024 blocks, partial (s,ss) per 1/64-slab ----------------
__global__ __launch_bounds__(256) void gn_part(const float* __restrict__ x,
                                               float* __restrict__ part) {
    int blk = blockIdx.x;            // bg = blk>>6 (16), slice = blk&63
    const f4* p = (const f4*)x + (size_t)(blk >> 6) * (CPG_ * N_ / 4) + (size_t)(blk & 63) * 512;
    float s = 0.f, ss = 0.f;
#pragma unroll
    for (int i = 0; i < 2; i++) {
        f4 v = p[threadIdx.x + i * 256];
#pragma unroll
        for (int j = 0; j < 4; j++) { float f = v[j]; s += f; ss += f * f; }
    }
#pragma unroll
    for (int off = 32; off > 0; off >>= 1) {
        s  += __shfl_down(s, off);
        ss += __shfl_down(ss, off);
    }
    __shared__ float rs[4], rss[4];
    int w = threadIdx.x >> 6;
    if ((threadIdx.x & 63) == 0) { rs[w] = s; rss[w] = ss; }
    __syncthreads();
    if (threadIdx.x == 0) {
        part[blk * 2]     = rs[0] + rs[1] + rs[2] + rs[3];
        part[blk * 2 + 1] = rss[0] + rss[1] + rss[2] + rss[3];
    }
}

// ---------------- GN apply (+inline stats reduce): x[b][c][n] f32 -> xnT[b][n][c] bf16 ----------
__global__ __launch_bounds__(256) void gn_apply(const float* __restrict__ x,
                                                const float* __restrict__ gw,
                                                const float* __restrict__ gb,
                                                const float* __restrict__ part,
                                                short* __restrict__ xnT) {
    int t = blockIdx.x * 256 + threadIdx.x;   // 0..262143
    int n  = t & 4095;                        // fastest across lanes -> coalesced reads
    int c0 = ((t >> 12) & 31) << 3;           // uniform per block
    int b  = t >> 17;                         // uniform per block
    int g  = c0 >> 5;
    int bg = b * 8 + g;
    // uniform scalar reduction of this (b,g)'s 64 partials
    float s = 0.f, ss = 0.f;
#pragma unroll 8
    for (int i = 0; i < 64; i++) {
        s  += part[bg * 128 + i * 2];
        ss += part[bg * 128 + i * 2 + 1];
    }
    const float inv = 1.f / (float)(CPG_ * N_);
    float mu   = s * inv;
    float var  = ss * inv - mu * mu;
    float rstd = rsqrtf(var + 1e-5f);

    const float* xp = x + ((size_t)b * C_ + c0) * N_ + n;
    short8 o;
#pragma unroll
    for (int j = 0; j < 8; j++) {
        float a  = rstd * gw[c0 + j];
        float bb = gb[c0 + j] - mu * a;
        o[j] = f2b(xp[(size_t)j * N_] * a + bb);
    }
    *(short8*)&xnT[((size_t)b * N_ + n) * C_ + c0] = o;
}

// ---------------- Fused QKV GEMM: out = W(256x256,f32->bf16) * xn(bf16) + bias(f32) ----------------
// which==0 -> Q transposed [b][n][c], scaled by qs (folded softmax scale);
// which==1 -> K transposed [b][n][c]; which==2 -> V [b][c][n].
__global__ __launch_bounds__(256) void gemm_qkv(
    const float* __restrict__ wq, const float* __restrict__ wk, const float* __restrict__ wv,
    const float* __restrict__ bq, const float* __restrict__ bk, const float* __restrict__ bv,
    const short* __restrict__ xnT,
    short* __restrict__ q, short* __restrict__ kt, short* __restrict__ v) {
    int z = blockIdx.z;
    int b = z / 3, which = z % 3;
    const float* W    = which == 0 ? wq : (which == 1 ? wk : wv);
    const float* bias = which == 0 ? bq : (which == 1 ? bk : bv);
    const short* X    = xnT + (size_t)b * N_ * C_;
    short* outp = which == 0 ? (q + (size_t)b * N_ * C_)
                : which == 1 ? (kt + (size_t)b * N_ * C_)
                             : (v + (size_t)b * C_ * N_);
    bool trans = (which != 2);
    // fold 1/sqrt(32)*log2(e) into Q so flash softmax is a raw exp2
    float mul = (which == 0) ? (0.17677669529663687f * 1.4426950408889634f) : 1.0f;

    __shared__ short wl[128][40];
    __shared__ short xl[128][40];

    int o0 = blockIdx.y * 128, n0 = blockIdx.x * 128;
    int tid = threadIdx.x;
    int w = tid >> 6, lane = tid & 63, li = lane & 15, quad = lane >> 4;
    int wr = w >> 1, wc = w & 1;

    f32x4 acc[4][4];
#pragma unroll
    for (int i = 0; i < 4; i++)
#pragma unroll
        for (int j = 0; j < 4; j++) acc[i][j] = (f32x4){0.f, 0.f, 0.f, 0.f};

    for (int k0 = 0; k0 < 256; k0 += 32) {
#pragma unroll
        for (int i = 0; i < 2; i++) {
            int idx = tid + i * 256;
            int row = idx >> 2, co = (idx & 3) << 3;
            const float* wp = &W[(size_t)(o0 + row) * 256 + k0 + co];
            f4 wa = *(const f4*)wp;
            f4 wb = *(const f4*)(wp + 4);
            short8 w8;
#pragma unroll
            for (int j = 0; j < 4; j++) { w8[j] = f2b(wa[j]); w8[j + 4] = f2b(wb[j]); }
            *(short8*)&wl[row][co] = w8;
            *(short8*)&xl[row][co] = *(const short8*)&X[(size_t)(n0 + row) * 256 + k0 + co];
        }
        __syncthreads();
        typedef short row40[40];
        row40* at = trans ? xl : wl;
        row40* bt = trans ? wl : xl;
        short8 af[4], bfr[4];
#pragma unroll
        for (int i = 0; i < 4; i++) af[i]  = *(short8*)&at[wr * 64 + i * 16 + li][quad * 8];
#pragma unroll
        for (int j = 0; j < 4; j++) bfr[j] = *(short8*)&bt[wc * 64 + j * 16 + li][quad * 8];
#pragma unroll
        for (int i = 0; i < 4; i++)
#pragma unroll
            for (int j = 0; j < 4; j++)
                acc[i][j] = __builtin_amdgcn_mfma_f32_16x16x32_bf16(af[i], bfr[j], acc[i][j], 0, 0, 0);
        __syncthreads();
    }

    if (!trans) {
#pragma unroll
        for (int i = 0; i < 4; i++) {
            int ob = o0 + wr * 64 + i * 16 + quad * 4;
#pragma unroll
            for (int j = 0; j < 4; j++) {
                int n_ = n0 + wc * 64 + j * 16 + li;
#pragma unroll
                for (int r = 0; r < 4; r++) {
                    float val = acc[i][j][r] + bias[ob + r];
                    outp[(size_t)(ob + r) * N_ + n_] = f2b(val);
                }
            }
        }
    } else {
#pragma unroll
        for (int i = 0; i < 4; i++) {
            int nb = n0 + wr * 64 + i * 16 + quad * 4;
#pragma unroll
            for (int j = 0; j < 4; j++) {
                int o_ = o0 + wc * 64 + j * 16 + li;
                float bv_ = bias[o_];
#pragma unroll
                for (int r = 0; r < 4; r++)
                    outp[(size_t)(nb + r) * C_ + o_] = f2b((acc[i][j][r] + bv_) * mul);
            }
        }
    }
}

// ---------------- Flash v5: 4-wave blocks, split-m, barrier-free loop, LDS combine ----------------
// QT: [b][n][c] (pre-scaled), KT: [b][m][c], V: [b][c][m]; O -> aoT [b][n][c].
// Each wave: same 32 Q-rows, disjoint 16 m-tiles. Partial (O,l) summed via LDS at end
// (no-max softmax => partials exactly additive, no rescale).
#define LOAD_TILE(m0, kf, vf)                                                          \
    do {                                                                               \
        _Pragma("unroll")                                                              \
        for (int c = 0; c < 4; c++)                                                    \
            kf[c] = *(const short8*)(kp + (size_t)((m0) + c * 16) * C_);               \
        _Pragma("unroll")                                                              \
        for (int kc = 0; kc < 2; kc++)                                                 \
            _Pragma("unroll")                                                          \
            for (int hf = 0; hf < 2; hf++)                                             \
                vf[kc * 2 + hf] =                                                      \
                    *(const short8*)(vp + (size_t)hf * 16 * N_ + (m0) + kc * 32);      \
    } while (0)

#define COMPUTE_TILE(kf, vf)                                                           \
    do {                                                                               \
        f32x4 s[2][4];                                                                 \
        _Pragma("unroll")                                                              \
        for (int c = 0; c < 4; c++) {                                                  \
            s[0][c] = __builtin_amdgcn_mfma_f32_16x16x32_bf16(kf[c], qf[0], zero, 0, 0, 0); \
            s[1][c] = __builtin_amdgcn_mfma_f32_16x16x32_bf16(kf[c], qf[1], zero, 0, 0, 0); \
        }                                                                              \
        _Pragma("unroll")                                                              \
        for (int g = 0; g < 2; g++) {                                                  \
            short* plw = plw_base + g * (16 * 72);                                     \
            float lp = 0.f;                                                            \
            _Pragma("unroll")                                                          \
            for (int c = 0; c < 4; c++) {                                              \
                float e0 = exp2f(s[g][c][0]);                                          \
                float e1 = exp2f(s[g][c][1]);                                          \
                float e2 = exp2f(s[g][c][2]);                                          \
                float e3 = exp2f(s[g][c][3]);                                          \
                lp += (e0 + e1) + (e2 + e3);                                           \
                unsigned pk0 = __builtin_amdgcn_perm(__float_as_uint(e1),              \
                                                     __float_as_uint(e0), 0x07060302); \
                unsigned pk1 = __builtin_amdgcn_perm(__float_as_uint(e3),              \
                                                     __float_as_uint(e2), 0x07060302); \
                uint2 pkv; pkv.x = pk0; pkv.y = pk1;                                   \
                *(uint2*)&plw[li * 72 + c * 16 + quad * 4] = pkv;                      \
            }                                                                          \
            lr[g] += lp;                                                               \
        }                                                                              \
        _Pragma("unroll")                                                              \
        for (int g = 0; g < 2; g++) {                                                  \
            short* plw = plw_base + g * (16 * 72);                                     \
            _Pragma("unroll")                                                          \
            for (int kc = 0; kc < 2; kc++) {                                           \
                short8 pf = *(short8*)&plw[li * 72 + kc * 32 + quad * 8];              \
                oa[g][0] = __builtin_amdgcn_mfma_f32_16x16x32_bf16(pf, vf[kc * 2 + 0], \
                                                                   oa[g][0], 0, 0, 0); \
                oa[g][1] = __builtin_amdgcn_mfma_f32_16x16x32_bf16(pf, vf[kc * 2 + 1], \
                                                                   oa[g][1], 0, 0, 0); \
            }                                                                          \
        }                                                                              \
    } while (0)

__global__ __launch_bounds__(256) void flash(const short* __restrict__ q,
                                             const short* __restrict__ kt,
                                             const short* __restrict__ v,
                                             short* __restrict__ aoT) {
    int b = blockIdx.z, h = blockIdx.y, nb = blockIdx.x;   // nb: 0..127
    const short* QT = q  + (size_t)b * N_ * C_ + h * HD_;  // QT[n*256 + d], pre-scaled
    const short* KT = kt + (size_t)b * N_ * C_ + h * HD_;  // KT[m*256 + d]
    const short* V  = v  + ((size_t)b * C_ + h * HD_) * N_;// V[d][m]
    short* O = aoT + (size_t)b * N_ * C_ + h * HD_;        // O[n*256 + d]

    // per-wave P buffer (2304 shorts = 4608 B); reused post-loop as float partial arena
    __shared__ short pl[4 * 2 * 16 * 72];

    int tid = threadIdx.x, w = tid >> 6, lane = tid & 63, li = lane & 15, quad = lane >> 4;
    int n0 = nb * 32;
    short* plw_base = pl + w * (2 * 16 * 72);

    short8 qf[2];   // B-frag of Q: B[k=d=quad*8+j][col n=li]; one b128 load per group
#pragma unroll
    for (int g = 0; g < 2; g++)
        qf[g] = *(const short8*)&QT[(size_t)(n0 + g * 16 + li) * 256 + quad * 8];

    f32x4 oa[2][2];  // [group][d-half]: rows n=quad*4+r, cols d=half*16+li
#pragma unroll
    for (int g = 0; g < 2; g++)
#pragma unroll
        for (int hf = 0; hf < 2; hf++) oa[g][hf] = (f32x4){0.f, 0.f, 0.f, 0.f};
    float lr[2] = {0.f, 0.f};
    const f32x4 zero = (f32x4){0.f, 0.f, 0.f, 0.f};

    const short* kp = KT + (size_t)li * C_ + quad * 8;   // + m*256
    const short* vp = V + (size_t)li * N_ + quad * 8;    // + half*16*N + m

    int mbase = w * 1024;   // this wave's m-range: [mbase, mbase+1024)
    short8 kfa[4], vfa[4], kfb[4], vfb[4];   // named buffers: all indices compile-time
    LOAD_TILE(mbase, kfa, vfa);

    for (int mt = 0; mt < 16; mt += 2) {
        LOAD_TILE(mbase + (mt + 1) * 64, kfb, vfb);
        COMPUTE_TILE(kfa, vfa);
        if (mt < 14) LOAD_TILE(mbase + (mt + 2) * 64, kfa, vfa);
        COMPUTE_TILE(kfb, vfb);
    }

    // quad-combine partial denominators (same li = same n across quads)
#pragma unroll
    for (int g = 0; g < 2; g++) {
        lr[g] += __shfl_xor(lr[g], 16);
        lr[g] += __shfl_xor(lr[g], 32);
    }

    // write this wave's partials into ITS OWN pl slice (float overlay; same-wave ordering)
    float* fb = (float*)plw_base;   // [1024: O 32n x 32d][32: l]
#pragma unroll
    for (int g = 0; g < 2; g++)
#pragma unroll
        for (int hf = 0; hf < 2; hf++)
#pragma unroll
            for (int r = 0; r < 4; r++)
                fb[(g * 16 + quad * 4 + r) * 32 + hf * 16 + li] = oa[g][hf][r];
    if (quad == 0) {
        fb[1024 + li]      = lr[0];
        fb[1024 + 16 + li] = lr[1];
    }
    __syncthreads();

    // combine: 256 threads, each owns (n = tid>>3, d0 = (tid&7)*4)
    {
        int n = tid >> 3, d0 = (tid & 7) << 2;
        f4 acc = (f4){0.f, 0.f, 0.f, 0.f};
        float l = 0.f;
#pragma unroll
        for (int ww = 0; ww < 4; ww++) {
            const float* fw = (const float*)(pl + ww * (2 * 16 * 72));
            f4 ov = *(const f4*)&fw[n * 32 + d0];
            acc += ov;
            l += fw[1024 + n];
        }
        float inv = 1.f / l;
        s4v st;
#pragma unroll
        for (int j = 0; j < 4; j++) st[j] = f2b(acc[j] * inv);
        *(s4v*)&O[(size_t)(n0 + n) * 256 + d0] = st;
    }
}

// ---------------- Out projection + bias + residual -> d_out (f32) ----------------
__global__ __launch_bounds__(256) void gemm_out(const float* __restrict__ W,
                                                const float* __restrict__ bias,
                                                const short* __restrict__ aoT,
                                                const float* __restrict__ resid,
                                                float* __restrict__ out) {
    int b = blockIdx.z;
    const short* X = aoT + (size_t)b * N_ * C_;
    const float* R = resid + (size_t)b * C_ * N_;
    float* outp = out + (size_t)b * C_ * N_;

    __shared__ short wl[128][40];
    __shared__ short xl[128][40];

    int o0 = blockIdx.y * 128, n0 = blockIdx.x * 128;
    int tid = threadIdx.x;
    int w = tid >> 6, lane = tid & 63, li = lane & 15, quad = lane >> 4;
    int wr = w >> 1, wc = w & 1;

    f32x4 acc[4][4];
#pragma unroll
    for (int i = 0; i < 4; i++)
#pragma unroll
        for (int j = 0; j < 4; j++) acc[i][j] = (f32x4){0.f, 0.f, 0.f, 0.f};

    for (int k0 = 0; k0 < 256; k0 += 32) {
#pragma unroll
        for (int i = 0; i < 2; i++) {
            int idx = tid + i * 256;
            int row = idx >> 2, co = (idx & 3) << 3;
            const float* wp = &W[(size_t)(o0 + row) * 256 + k0 + co];
            f4 wa = *(const f4*)wp;
            f4 wb = *(const f4*)(wp + 4);
            short8 w8;
#pragma unroll
            for (int j = 0; j < 4; j++) { w8[j] = f2b(wa[j]); w8[j + 4] = f2b(wb[j]); }
            *(short8*)&wl[row][co] = w8;
            *(short8*)&xl[row][co] = *(const short8*)&X[(size_t)(n0 + row) * 256 + k0 + co];
        }
        __syncthreads();
        short8 af[4], bfr[4];
#pragma unroll
        for (int i = 0; i < 4; i++) af[i]  = *(short8*)&wl[wr * 64 + i * 16 + li][quad * 8];
#pragma unroll
        for (int j = 0; j < 4; j++) bfr[j] = *(short8*)&xl[wc * 64 + j * 16 + li][quad * 8];
#pragma unroll
        for (int i = 0; i < 4; i++)
#pragma unroll
            for (int j = 0; j < 4; j++)
                acc[i][j] = __builtin_amdgcn_mfma_f32_16x16x32_bf16(af[i], bfr[j], acc[i][j], 0, 0, 0);
        __syncthreads();
    }
#pragma unroll
    for (int i = 0; i < 4; i++) {
        int ob = o0 + wr * 64 + i * 16 + quad * 4;
#pragma unroll
        for (int j = 0; j < 4; j++) {
            int n_ = n0 + wc * 64 + j * 16 + li;
#pragma unroll
            for (int r = 0; r < 4; r++) {
                size_t idx = (size_t)(ob + r) * N_ + n_;
                outp[idx] = acc[i][j][r] + bias[ob + r] + R[idx];
            }
        }
    }
}

extern "C" void kernel_launch(void* const* d_in, const int* in_sizes, int n_in,
                              void* d_out, int out_size, void* d_ws, size_t ws_size,
                              hipStream_t stream) {
    const float* x  = (const float*)d_in[0];
    const float* gw = (const float*)d_in[1];
    const float* gb = (const float*)d_in[2];
    const float* wq = (const float*)d_in[3];
    const float* bq = (const float*)d_in[4];
    const float* wk = (const float*)d_in[5];
    const float* bk = (const float*)d_in[6];
    const float* wv = (const float*)d_in[7];
    const float* bv = (const float*)d_in[8];
    const float* wo = (const float*)d_in[9];
    const float* bo = (const float*)d_in[10];
    float* out = (float*)d_out;

    char* ws = (char*)d_ws;
    float* part = (float*)ws;             // 2048 floats
    const size_t TS = (size_t)B_ * N_ * C_;  // 2M elements per bf16 tensor
    short* xnT = (short*)(ws + 16384);
    short* q   = xnT + TS;
    short* kt  = q + TS;
    short* v   = kt + TS;
    short* aoT = xnT;  // alias: xnT dead after gemm_qkv

    gn_part<<<1024, 256, 0, stream>>>(x, part);
    gn_apply<<<1024, 256, 0, stream>>>(x, gw, gb, part, xnT);
    gemm_qkv<<<dim3(32, 2, 6), 256, 0, stream>>>(wq, wk, wv, bq, bk, bv, xnT, q, kt, v);
    flash<<<dim3(128, 8, 2), 256, 0, stream>>>(q, kt, v, aoT);
    gemm_out<<<dim3(32, 2, 2), 256, 0, stream>>>(wo, bo, aoT, x, out);
}

// Round 7
// 228.280 us; speedup vs baseline: 1.0213x; 1.0213x over previous
//
#include <hip/hip_runtime.h>

#define B_   2
#define C_   256
#define N_   4096
#define H_   8
#define HD_  32
#define G_   8
#define CPG_ 32

typedef short short8 __attribute__((ext_vector_type(8)));
typedef short s4v    __attribute__((ext_vector_type(4)));
typedef float f32x4  __attribute__((ext_vector_type(4)));
typedef float f4     __attribute__((ext_vector_type(4)));

__device__ __forceinline__ float b2f(short s) {
    return __uint_as_float(((unsigned)(unsigned short)s) << 16);
}
__device__ __forceinline__ short f2b(float f) {
    unsigned u = __float_as_uint(f);
    unsigned r = (u + 0x7FFF + ((u >> 16) & 1)) >> 16;  // RNE
    return (short)r;
}

// ---------------- GN stats stage 1: 1024 blocks, partial (s,ss) per 1/64-slab ----------------
__global__ __launch_bounds__(256) void gn_part(const float* __restrict__ x,
                                               float* __restrict__ part) {
    int blk = blockIdx.x;            // bg = blk>>6 (16), slice = blk&63
    const f4* p = (const f4*)x + (size_t)(blk >> 6) * (CPG_ * N_ / 4) + (size_t)(blk & 63) * 512;
    float s = 0.f, ss = 0.f;
#pragma unroll
    for (int i = 0; i < 2; i++) {
        f4 v = p[threadIdx.x + i * 256];
#pragma unroll
        for (int j = 0; j < 4; j++) { float f = v[j]; s += f; ss += f * f; }
    }
#pragma unroll
    for (int off = 32; off > 0; off >>= 1) {
        s  += __shfl_down(s, off);
        ss += __shfl_down(ss, off);
    }
    __shared__ float rs[4], rss[4];
    int w = threadIdx.x >> 6;
    if ((threadIdx.x & 63) == 0) { rs[w] = s; rss[w] = ss; }
    __syncthreads();
    if (threadIdx.x == 0) {
        part[blk * 2]     = rs[0] + rs[1] + rs[2] + rs[3];
        part[blk * 2 + 1] = rss[0] + rss[1] + rss[2] + rss[3];
    }
}

// ---------------- GN apply (+inline stats reduce): x[b][c][n] f32 -> xnT[b][n][c] bf16 ----------
__global__ __launch_bounds__(256) void gn_apply(const float* __restrict__ x,
                                                const float* __restrict__ gw,
                                                const float* __restrict__ gb,
                                                const float* __restrict__ part,
                                                short* __restrict__ xnT) {
    int t = blockIdx.x * 256 + threadIdx.x;   // 0..262143
    int n  = t & 4095;                        // fastest across lanes -> coalesced reads
    int c0 = ((t >> 12) & 31) << 3;           // uniform per block
    int b  = t >> 17;                         // uniform per block
    int g  = c0 >> 5;
    int bg = b * 8 + g;
    // uniform scalar reduction of this (b,g)'s 64 partials
    float s = 0.f, ss = 0.f;
#pragma unroll 8
    for (int i = 0; i < 64; i++) {
        s  += part[bg * 128 + i * 2];
        ss += part[bg * 128 + i * 2 + 1];
    }
    const float inv = 1.f / (float)(CPG_ * N_);
    float mu   = s * inv;
    float var  = ss * inv - mu * mu;
    float rstd = rsqrtf(var + 1e-5f);

    const float* xp = x + ((size_t)b * C_ + c0) * N_ + n;
    short8 o;
#pragma unroll
    for (int j = 0; j < 8; j++) {
        float a  = rstd * gw[c0 + j];
        float bb = gb[c0 + j] - mu * a;
        o[j] = f2b(xp[(size_t)j * N_] * a + bb);
    }
    *(short8*)&xnT[((size_t)b * N_ + n) * C_ + c0] = o;
}

// ---------------- Fused QKV GEMM: out = W(256x256,f32->bf16) * xn(bf16) + bias(f32) ----------------
// which==0 -> Q transposed [b][n][c], scaled by qs (folded softmax scale);
// which==1 -> K transposed [b][n][c]; which==2 -> V [b][c][n].
__global__ __launch_bounds__(256) void gemm_qkv(
    const float* __restrict__ wq, const float* __restrict__ wk, const float* __restrict__ wv,
    const float* __restrict__ bq, const float* __restrict__ bk, const float* __restrict__ bv,
    const short* __restrict__ xnT,
    short* __restrict__ q, short* __restrict__ kt, short* __restrict__ v) {
    int z = blockIdx.z;
    int b = z / 3, which = z % 3;
    const float* W    = which == 0 ? wq : (which == 1 ? wk : wv);
    const float* bias = which == 0 ? bq : (which == 1 ? bk : bv);
    const short* X    = xnT + (size_t)b * N_ * C_;
    short* outp = which == 0 ? (q + (size_t)b * N_ * C_)
                : which == 1 ? (kt + (size_t)b * N_ * C_)
                             : (v + (size_t)b * C_ * N_);
    bool trans = (which != 2);
    // fold 1/sqrt(32)*log2(e) into Q so flash softmax is a raw exp2
    float mul = (which == 0) ? (0.17677669529663687f * 1.4426950408889634f) : 1.0f;

    __shared__ short wl[128][40];
    __shared__ short xl[128][40];

    int o0 = blockIdx.y * 128, n0 = blockIdx.x * 128;
    int tid = threadIdx.x;
    int w = tid >> 6, lane = tid & 63, li = lane & 15, quad = lane >> 4;
    int wr = w >> 1, wc = w & 1;

    f32x4 acc[4][4];
#pragma unroll
    for (int i = 0; i < 4; i++)
#pragma unroll
        for (int j = 0; j < 4; j++) acc[i][j] = (f32x4){0.f, 0.f, 0.f, 0.f};

    for (int k0 = 0; k0 < 256; k0 += 32) {
#pragma unroll
        for (int i = 0; i < 2; i++) {
            int idx = tid + i * 256;
            int row = idx >> 2, co = (idx & 3) << 3;
            const float* wp = &W[(size_t)(o0 + row) * 256 + k0 + co];
            f4 wa = *(const f4*)wp;
            f4 wb = *(const f4*)(wp + 4);
            short8 w8;
#pragma unroll
            for (int j = 0; j < 4; j++) { w8[j] = f2b(wa[j]); w8[j + 4] = f2b(wb[j]); }
            *(short8*)&wl[row][co] = w8;
            *(short8*)&xl[row][co] = *(const short8*)&X[(size_t)(n0 + row) * 256 + k0 + co];
        }
        __syncthreads();
        typedef short row40[40];
        row40* at = trans ? xl : wl;
        row40* bt = trans ? wl : xl;
        short8 af[4], bfr[4];
#pragma unroll
        for (int i = 0; i < 4; i++) af[i]  = *(short8*)&at[wr * 64 + i * 16 + li][quad * 8];
#pragma unroll
        for (int j = 0; j < 4; j++) bfr[j] = *(short8*)&bt[wc * 64 + j * 16 + li][quad * 8];
#pragma unroll
        for (int i = 0; i < 4; i++)
#pragma unroll
            for (int j = 0; j < 4; j++)
                acc[i][j] = __builtin_amdgcn_mfma_f32_16x16x32_bf16(af[i], bfr[j], acc[i][j], 0, 0, 0);
        __syncthreads();
    }

    if (!trans) {
#pragma unroll
        for (int i = 0; i < 4; i++) {
            int ob = o0 + wr * 64 + i * 16 + quad * 4;
#pragma unroll
            for (int j = 0; j < 4; j++) {
                int n_ = n0 + wc * 64 + j * 16 + li;
#pragma unroll
                for (int r = 0; r < 4; r++) {
                    float val = acc[i][j][r] + bias[ob + r];
                    outp[(size_t)(ob + r) * N_ + n_] = f2b(val);
                }
            }
        }
    } else {
#pragma unroll
        for (int i = 0; i < 4; i++) {
            int nb = n0 + wr * 64 + i * 16 + quad * 4;
#pragma unroll
            for (int j = 0; j < 4; j++) {
                int o_ = o0 + wc * 64 + j * 16 + li;
                float bv_ = bias[o_];
#pragma unroll
                for (int r = 0; r < 4; r++)
                    outp[(size_t)(nb + r) * C_ + o_] = f2b((acc[i][j][r] + bv_) * mul);
            }
        }
    }
}

// ---------------- Flash v6: v5 + XCD-aware (b,h) grouping + raw v_exp ----------------
// All 128 n-blocks of one (b,h) land on one XCD (blockIdx & 7) so its 512 KB K/V slab
// stays L2-resident (2 head-pairs = 1 MB per 4 MiB XCD L2).
#define LOAD_TILE(m0, kf, vf)                                                          \
    do {                                                                               \
        _Pragma("unroll")                                                              \
        for (int c = 0; c < 4; c++)                                                    \
            kf[c] = *(const short8*)(kp + (size_t)((m0) + c * 16) * C_);               \
        _Pragma("unroll")                                                              \
        for (int kc = 0; kc < 2; kc++)                                                 \
            _Pragma("unroll")                                                          \
            for (int hf = 0; hf < 2; hf++)                                             \
                vf[kc * 2 + hf] =                                                      \
                    *(const short8*)(vp + (size_t)hf * 16 * N_ + (m0) + kc * 32);      \
    } while (0)

#define COMPUTE_TILE(kf, vf)                                                           \
    do {                                                                               \
        f32x4 s[2][4];                                                                 \
        _Pragma("unroll")                                                              \
        for (int c = 0; c < 4; c++) {                                                  \
            s[0][c] = __builtin_amdgcn_mfma_f32_16x16x32_bf16(kf[c], qf[0], zero, 0, 0, 0); \
            s[1][c] = __builtin_amdgcn_mfma_f32_16x16x32_bf16(kf[c], qf[1], zero, 0, 0, 0); \
        }                                                                              \
        _Pragma("unroll")                                                              \
        for (int g = 0; g < 2; g++) {                                                  \
            short* plw = plw_base + g * (16 * 72);                                     \
            float lp = 0.f;                                                            \
            _Pragma("unroll")                                                          \
            for (int c = 0; c < 4; c++) {                                              \
                float e0 = __builtin_amdgcn_exp2f(s[g][c][0]);                         \
                float e1 = __builtin_amdgcn_exp2f(s[g][c][1]);                         \
                float e2 = __builtin_amdgcn_exp2f(s[g][c][2]);                         \
                float e3 = __builtin_amdgcn_exp2f(s[g][c][3]);                         \
                lp += (e0 + e1) + (e2 + e3);                                           \
                unsigned pk0 = __builtin_amdgcn_perm(__float_as_uint(e1),              \
                                                     __float_as_uint(e0), 0x07060302); \
                unsigned pk1 = __builtin_amdgcn_perm(__float_as_uint(e3),              \
                                                     __float_as_uint(e2), 0x07060302); \
                uint2 pkv; pkv.x = pk0; pkv.y = pk1;                                   \
                *(uint2*)&plw[li * 72 + c * 16 + quad * 4] = pkv;                      \
            }                                                                          \
            lr[g] += lp;                                                               \
        }                                                                              \
        _Pragma("unroll")                                                              \
        for (int g = 0; g < 2; g++) {                                                  \
            short* plw = plw_base + g * (16 * 72);                                     \
            _Pragma("unroll")                                                          \
            for (int kc = 0; kc < 2; kc++) {                                           \
                short8 pf = *(short8*)&plw[li * 72 + kc * 32 + quad * 8];              \
                oa[g][0] = __builtin_amdgcn_mfma_f32_16x16x32_bf16(pf, vf[kc * 2 + 0], \
                                                                   oa[g][0], 0, 0, 0); \
                oa[g][1] = __builtin_amdgcn_mfma_f32_16x16x32_bf16(pf, vf[kc * 2 + 1], \
                                                                   oa[g][1], 0, 0, 0); \
            }                                                                          \
        }                                                                              \
    } while (0)

__global__ __launch_bounds__(256) void flash(const short* __restrict__ q,
                                             const short* __restrict__ kt,
                                             const short* __restrict__ v,
                                             short* __restrict__ aoT) {
    // XCD-aware decode: all blocks of one (b,h) share blockIdx%8 -> same XCD L2
    int bid = blockIdx.x;          // 0..2047
    int r = bid & 7;               // XCD
    int s_ = bid >> 3;             // 0..255
    int p = r * 2 + (s_ & 1);      // head-pair 0..15
    int nb = s_ >> 1;              // 0..127
    int b = p >> 3, h = p & 7;

    const short* QT = q  + (size_t)b * N_ * C_ + h * HD_;  // QT[n*256 + d], pre-scaled
    const short* KT = kt + (size_t)b * N_ * C_ + h * HD_;  // KT[m*256 + d]
    const short* V  = v  + ((size_t)b * C_ + h * HD_) * N_;// V[d][m]
    short* O = aoT + (size_t)b * N_ * C_ + h * HD_;        // O[n*256 + d]

    // per-wave P buffer (2304 shorts = 4608 B); reused post-loop as float partial arena
    __shared__ short pl[4 * 2 * 16 * 72];

    int tid = threadIdx.x, w = tid >> 6, lane = tid & 63, li = lane & 15, quad = lane >> 4;
    int n0 = nb * 32;
    short* plw_base = pl + w * (2 * 16 * 72);

    short8 qf[2];   // B-frag of Q: B[k=d=quad*8+j][col n=li]; one b128 load per group
#pragma unroll
    for (int g = 0; g < 2; g++)
        qf[g] = *(const short8*)&QT[(size_t)(n0 + g * 16 + li) * 256 + quad * 8];

    f32x4 oa[2][2];  // [group][d-half]: rows n=quad*4+r, cols d=half*16+li
#pragma unroll
    for (int g = 0; g < 2; g++)
#pragma unroll
        for (int hf = 0; hf < 2; hf++) oa[g][hf] = (f32x4){0.f, 0.f, 0.f, 0.f};
    float lr[2] = {0.f, 0.f};
    const f32x4 zero = (f32x4){0.f, 0.f, 0.f, 0.f};

    const short* kp = KT + (size_t)li * C_ + quad * 8;   // + m*256
    const short* vp = V + (size_t)li * N_ + quad * 8;    // + half*16*N + m

    int mbase = w * 1024;   // this wave's m-range: [mbase, mbase+1024)
    short8 kfa[4], vfa[4], kfb[4], vfb[4];   // named buffers: all indices compile-time
    LOAD_TILE(mbase, kfa, vfa);

    for (int mt = 0; mt < 16; mt += 2) {
        LOAD_TILE(mbase + (mt + 1) * 64, kfb, vfb);
        COMPUTE_TILE(kfa, vfa);
        if (mt < 14) LOAD_TILE(mbase + (mt + 2) * 64, kfa, vfa);
        COMPUTE_TILE(kfb, vfb);
    }

    // quad-combine partial denominators (same li = same n across quads)
#pragma unroll
    for (int g = 0; g < 2; g++) {
        lr[g] += __shfl_xor(lr[g], 16);
        lr[g] += __shfl_xor(lr[g], 32);
    }

    // write this wave's partials into ITS OWN pl slice (float overlay; same-wave ordering)
    float* fb = (float*)plw_base;   // [1024: O 32n x 32d][32: l]
#pragma unroll
    for (int g = 0; g < 2; g++)
#pragma unroll
        for (int hf = 0; hf < 2; hf++)
#pragma unroll
            for (int r2 = 0; r2 < 4; r2++)
                fb[(g * 16 + quad * 4 + r2) * 32 + hf * 16 + li] = oa[g][hf][r2];
    if (quad == 0) {
        fb[1024 + li]      = lr[0];
        fb[1024 + 16 + li] = lr[1];
    }
    __syncthreads();

    // combine: 256 threads, each owns (n = tid>>3, d0 = (tid&7)*4)
    {
        int n = tid >> 3, d0 = (tid & 7) << 2;
        f4 acc = (f4){0.f, 0.f, 0.f, 0.f};
        float l = 0.f;
#pragma unroll
        for (int ww = 0; ww < 4; ww++) {
            const float* fw = (const float*)(pl + ww * (2 * 16 * 72));
            f4 ov = *(const f4*)&fw[n * 32 + d0];
            acc += ov;
            l += fw[1024 + n];
        }
        float inv = 1.f / l;
        s4v st;
#pragma unroll
        for (int j = 0; j < 4; j++) st[j] = f2b(acc[j] * inv);
        *(s4v*)&O[(size_t)(n0 + n) * 256 + d0] = st;
    }
}

// ---------------- Out projection + bias + residual -> d_out (f32) ----------------
__global__ __launch_bounds__(256) void gemm_out(const float* __restrict__ W,
                                                const float* __restrict__ bias,
                                                const short* __restrict__ aoT,
                                                const float* __restrict__ resid,
                                                float* __restrict__ out) {
    int b = blockIdx.z;
    const short* X = aoT + (size_t)b * N_ * C_;
    const float* R = resid + (size_t)b * C_ * N_;
    float* outp = out + (size_t)b * C_ * N_;

    __shared__ short wl[128][40];
    __shared__ short xl[128][40];

    int o0 = blockIdx.y * 128, n0 = blockIdx.x * 128;
    int tid = threadIdx.x;
    int w = tid >> 6, lane = tid & 63, li = lane & 15, quad = lane >> 4;
    int wr = w >> 1, wc = w & 1;

    f32x4 acc[4][4];
#pragma unroll
    for (int i = 0; i < 4; i++)
#pragma unroll
        for (int j = 0; j < 4; j++) acc[i][j] = (f32x4){0.f, 0.f, 0.f, 0.f};

    for (int k0 = 0; k0 < 256; k0 += 32) {
#pragma unroll
        for (int i = 0; i < 2; i++) {
            int idx = tid + i * 256;
            int row = idx >> 2, co = (idx & 3) << 3;
            const float* wp = &W[(size_t)(o0 + row) * 256 + k0 + co];
            f4 wa = *(const f4*)wp;
            f4 wb = *(const f4*)(wp + 4);
            short8 w8;
#pragma unroll
            for (int j = 0; j < 4; j++) { w8[j] = f2b(wa[j]); w8[j + 4] = f2b(wb[j]); }
            *(short8*)&wl[row][co] = w8;
            *(short8*)&xl[row][co] = *(const short8*)&X[(size_t)(n0 + row) * 256 + k0 + co];
        }
        __syncthreads();
        short8 af[4], bfr[4];
#pragma unroll
        for (int i = 0; i < 4; i++) af[i]  = *(short8*)&wl[wr * 64 + i * 16 + li][quad * 8];
#pragma unroll
        for (int j = 0; j < 4; j++) bfr[j] = *(short8*)&xl[wc * 64 + j * 16 + li][quad * 8];
#pragma unroll
        for (int i = 0; i < 4; i++)
#pragma unroll
            for (int j = 0; j < 4; j++)
                acc[i][j] = __builtin_amdgcn_mfma_f32_16x16x32_bf16(af[i], bfr[j], acc[i][j], 0, 0, 0);
        __syncthreads();
    }
#pragma unroll
    for (int i = 0; i < 4; i++) {
        int ob = o0 + wr * 64 + i * 16 + quad * 4;
#pragma unroll
        for (int j = 0; j < 4; j++) {
            int n_ = n0 + wc * 64 + j * 16 + li;
#pragma unroll
            for (int r = 0; r < 4; r++) {
                size_t idx = (size_t)(ob + r) * N_ + n_;
                outp[idx] = acc[i][j][r] + bias[ob + r] + R[idx];
            }
        }
    }
}

extern "C" void kernel_launch(void* const* d_in, const int* in_sizes, int n_in,
                              void* d_out, int out_size, void* d_ws, size_t ws_size,
                              hipStream_t stream) {
    const float* x  = (const float*)d_in[0];
    const float* gw = (const float*)d_in[1];
    const float* gb = (const float*)d_in[2];
    const float* wq = (const float*)d_in[3];
    const float* bq = (const float*)d_in[4];
    const float* wk = (const float*)d_in[5];
    const float* bk = (const float*)d_in[6];
    const float* wv = (const float*)d_in[7];
    const float* bv = (const float*)d_in[8];
    const float* wo = (const float*)d_in[9];
    const float* bo = (const float*)d_in[10];
    float* out = (float*)d_out;

    char* ws = (char*)d_ws;
    float* part = (float*)ws;             // 2048 floats
    const size_t TS = (size_t)B_ * N_ * C_;  // 2M elements per bf16 tensor
    short* xnT = (short*)(ws + 16384);
    short* q   = xnT + TS;
    short* kt  = q + TS;
    short* v   = kt + TS;
    short* aoT = xnT;  // alias: xnT dead after gemm_qkv

    gn_part<<<1024, 256, 0, stream>>>(x, part);
    gn_apply<<<1024, 256, 0, stream>>>(x, gw, gb, part, xnT);
    gemm_qkv<<<dim3(32, 2, 6), 256, 0, stream>>>(wq, wk, wv, bq, bk, bv, xnT, q, kt, v);
    flash<<<2048, 256, 0, stream>>>(q, kt, v, aoT);
    gemm_out<<<dim3(32, 2, 2), 256, 0, stream>>>(wo, bo, aoT, x, out);
}

// Round 8
// 182.669 us; speedup vs baseline: 1.2763x; 1.2497x over previous
//
#include <hip/hip_runtime.h>

#define B_   2
#define C_   256
#define N_   4096
#define H_   8
#define HD_  32
#define G_   8
#define CPG_ 32

typedef short short8 __attribute__((ext_vector_type(8)));
typedef short s4v    __attribute__((ext_vector_type(4)));
typedef float f32x4  __attribute__((ext_vector_type(4)));
typedef float f4     __attribute__((ext_vector_type(4)));

__device__ __forceinline__ float b2f(short s) {
    return __uint_as_float(((unsigned)(unsigned short)s) << 16);
}
__device__ __forceinline__ short f2b(float f) {
    unsigned u = __float_as_uint(f);
    unsigned r = (u + 0x7FFF + ((u >> 16) & 1)) >> 16;  // RNE
    return (short)r;
}

// ---------------- GN stats stage 1: 1024 blocks, partial (s,ss) per 1/64-slab ----------------
__global__ __launch_bounds__(256) void gn_part(const float* __restrict__ x,
                                               float* __restrict__ part) {
    int blk = blockIdx.x;            // bg = blk>>6 (16), slice = blk&63
    const f4* p = (const f4*)x + (size_t)(blk >> 6) * (CPG_ * N_ / 4) + (size_t)(blk & 63) * 512;
    float s = 0.f, ss = 0.f;
#pragma unroll
    for (int i = 0; i < 2; i++) {
        f4 v = p[threadIdx.x + i * 256];
#pragma unroll
        for (int j = 0; j < 4; j++) { float f = v[j]; s += f; ss += f * f; }
    }
#pragma unroll
    for (int off = 32; off > 0; off >>= 1) {
        s  += __shfl_down(s, off);
        ss += __shfl_down(ss, off);
    }
    __shared__ float rs[4], rss[4];
    int w = threadIdx.x >> 6;
    if ((threadIdx.x & 63) == 0) { rs[w] = s; rss[w] = ss; }
    __syncthreads();
    if (threadIdx.x == 0) {
        part[blk * 2]     = rs[0] + rs[1] + rs[2] + rs[3];
        part[blk * 2 + 1] = rss[0] + rss[1] + rss[2] + rss[3];
    }
}

// ---------------- GN apply (+inline stats reduce): x[b][c][n] f32 -> xnT[b][n][c] bf16 ----------
__global__ __launch_bounds__(256) void gn_apply(const float* __restrict__ x,
                                                const float* __restrict__ gw,
                                                const float* __restrict__ gb,
                                                const float* __restrict__ part,
                                                short* __restrict__ xnT) {
    int t = blockIdx.x * 256 + threadIdx.x;   // 0..262143
    int n  = t & 4095;                        // fastest across lanes -> coalesced reads
    int c0 = ((t >> 12) & 31) << 3;           // uniform per block
    int b  = t >> 17;                         // uniform per block
    int g  = c0 >> 5;
    int bg = b * 8 + g;
    // uniform scalar reduction of this (b,g)'s 64 partials
    float s = 0.f, ss = 0.f;
#pragma unroll 8
    for (int i = 0; i < 64; i++) {
        s  += part[bg * 128 + i * 2];
        ss += part[bg * 128 + i * 2 + 1];
    }
    const float inv = 1.f / (float)(CPG_ * N_);
    float mu   = s * inv;
    float var  = ss * inv - mu * mu;
    float rstd = rsqrtf(var + 1e-5f);

    const float* xp = x + ((size_t)b * C_ + c0) * N_ + n;
    short8 o;
#pragma unroll
    for (int j = 0; j < 8; j++) {
        float a  = rstd * gw[c0 + j];
        float bb = gb[c0 + j] - mu * a;
        o[j] = f2b(xp[(size_t)j * N_] * a + bb);
    }
    *(short8*)&xnT[((size_t)b * N_ + n) * C_ + c0] = o;
}

// ---------------- Fused QKV GEMM: out = W(256x256,f32->bf16) * xn(bf16) + bias(f32) ----------------
// which==0 -> Q transposed [b][n][c], scaled (folded softmax scale);
// which==1 -> K packed per head [b*8+h][m][32] (operand swap);
// which==2 -> V [b][c][n].
__global__ __launch_bounds__(256) void gemm_qkv(
    const float* __restrict__ wq, const float* __restrict__ wk, const float* __restrict__ wv,
    const float* __restrict__ bq, const float* __restrict__ bk, const float* __restrict__ bv,
    const short* __restrict__ xnT,
    short* __restrict__ q, short* __restrict__ kt, short* __restrict__ v) {
    int z = blockIdx.z;
    int b = z / 3, which = z % 3;
    const float* W    = which == 0 ? wq : (which == 1 ? wk : wv);
    const float* bias = which == 0 ? bq : (which == 1 ? bk : bv);
    const short* X    = xnT + (size_t)b * N_ * C_;
    bool trans = (which != 2);
    float mul = (which == 0) ? (0.17677669529663687f * 1.4426950408889634f) : 1.0f;

    __shared__ short wl[128][40];
    __shared__ short xl[128][40];

    int o0 = blockIdx.y * 128, n0 = blockIdx.x * 128;
    int tid = threadIdx.x;
    int w = tid >> 6, lane = tid & 63, li = lane & 15, quad = lane >> 4;
    int wr = w >> 1, wc = w & 1;

    f32x4 acc[4][4];
#pragma unroll
    for (int i = 0; i < 4; i++)
#pragma unroll
        for (int j = 0; j < 4; j++) acc[i][j] = (f32x4){0.f, 0.f, 0.f, 0.f};

    for (int k0 = 0; k0 < 256; k0 += 32) {
#pragma unroll
        for (int i = 0; i < 2; i++) {
            int idx = tid + i * 256;
            int row = idx >> 2, co = (idx & 3) << 3;
            const float* wp = &W[(size_t)(o0 + row) * 256 + k0 + co];
            f4 wa = *(const f4*)wp;
            f4 wb = *(const f4*)(wp + 4);
            short8 w8;
#pragma unroll
            for (int j = 0; j < 4; j++) { w8[j] = f2b(wa[j]); w8[j + 4] = f2b(wb[j]); }
            *(short8*)&wl[row][co] = w8;
            *(short8*)&xl[row][co] = *(const short8*)&X[(size_t)(n0 + row) * 256 + k0 + co];
        }
        __syncthreads();
        typedef short row40[40];
        row40* at = trans ? xl : wl;
        row40* bt = trans ? wl : xl;
        short8 af[4], bfr[4];
#pragma unroll
        for (int i = 0; i < 4; i++) af[i]  = *(short8*)&at[wr * 64 + i * 16 + li][quad * 8];
#pragma unroll
        for (int j = 0; j < 4; j++) bfr[j] = *(short8*)&bt[wc * 64 + j * 16 + li][quad * 8];
#pragma unroll
        for (int i = 0; i < 4; i++)
#pragma unroll
            for (int j = 0; j < 4; j++)
                acc[i][j] = __builtin_amdgcn_mfma_f32_16x16x32_bf16(af[i], bfr[j], acc[i][j], 0, 0, 0);
        __syncthreads();
    }

    if (which == 2) {          // V [b][c][n]
        short* outp = v + (size_t)b * C_ * N_;
#pragma unroll
        for (int i = 0; i < 4; i++) {
            int ob = o0 + wr * 64 + i * 16 + quad * 4;
#pragma unroll
            for (int j = 0; j < 4; j++) {
                int n_ = n0 + wc * 64 + j * 16 + li;
#pragma unroll
                for (int r = 0; r < 4; r++) {
                    float val = acc[i][j][r] + bias[ob + r];
                    outp[(size_t)(ob + r) * N_ + n_] = f2b(val);
                }
            }
        }
    } else if (which == 0) {   // Q^T [b][n][c], scaled
        short* outp = q + (size_t)b * N_ * C_;
#pragma unroll
        for (int i = 0; i < 4; i++) {
            int nb_ = n0 + wr * 64 + i * 16 + quad * 4;
#pragma unroll
            for (int j = 0; j < 4; j++) {
                int o_ = o0 + wc * 64 + j * 16 + li;
                float bv_ = bias[o_];
#pragma unroll
                for (int r = 0; r < 4; r++)
                    outp[(size_t)(nb_ + r) * C_ + o_] = f2b((acc[i][j][r] + bv_) * mul);
            }
        }
    } else {                   // K packed [b*8+h][m][32]
#pragma unroll
        for (int i = 0; i < 4; i++) {
            int nb_ = n0 + wr * 64 + i * 16 + quad * 4;
#pragma unroll
            for (int j = 0; j < 4; j++) {
                int o_ = o0 + wc * 64 + j * 16 + li;
                int hh = o_ >> 5, d = o_ & 31;
                float bv_ = bias[o_];
                short* kdst = kt + ((size_t)(b * 8 + hh) * N_) * HD_ + d;
#pragma unroll
                for (int r = 0; r < 4; r++)
                    kdst[(size_t)(nb_ + r) * HD_] = f2b(acc[i][j][r] + bv_);
            }
        }
    }
}

// ---------------- Flash v7: 128 Q-rows/block, LDS-shared dbuf K/V, 1 barrier/tile ----------------
// QT: [b][n][c] (pre-scaled); KP: [b*8+h][m][32] packed; V: [b][c][n]; O -> aoT [b][n][c].
// 4 waves own disjoint 32-row n-slices, share each K/V tile from LDS. Global K/V traffic
// = 512 blocks x 512 KB = 262 MB (4x less than v6). Lean no-max softmax (additive partials).
__global__ __launch_bounds__(256) void flash(const short* __restrict__ q,
                                             const short* __restrict__ ktp,
                                             const short* __restrict__ v,
                                             short* __restrict__ aoT) {
    // XCD-aware decode: all 32 blocks of one (b,h) share blockIdx%8 -> same XCD L2
    int bid = blockIdx.x;          // 0..511
    int xcd = bid & 7;
    int s_  = bid >> 3;            // 0..63
    int bh  = xcd * 2 + (s_ & 1);  // head-pair per XCD
    int nb  = s_ >> 1;             // 0..31
    int b = bh >> 3, h = bh & 7;

    const short* QT = q   + (size_t)b * N_ * C_ + h * HD_;   // QT[n*256 + d]
    const short* KP = ktp + (size_t)bh * N_ * HD_;           // KP[m*32 + d], packed
    const short* V  = v   + ((size_t)b * C_ + h * HD_) * N_; // V[d][m]
    short* O = aoT + (size_t)b * N_ * C_ + h * HD_;          // O[n*256 + d]

    __shared__ short kl[2][64 * 40];    // K tile [m][d], pad 40 (2-way free)
    __shared__ short vl[2][32 * 72];    // V tile [d][m], pad 72
    __shared__ short pl[4 * 2 * 16 * 72];  // per-wave P arenas

    int tid = threadIdx.x, w = tid >> 6, lane = tid & 63, li = lane & 15, quad = lane >> 4;
    int n0w = nb * 128 + w * 32;
    short* plw_base = pl + w * (2 * 16 * 72);

    short8 qf[2];   // B-frag of Q: B[k=d=quad*8+j][col n=li]
#pragma unroll
    for (int g = 0; g < 2; g++)
        qf[g] = *(const short8*)&QT[(size_t)(n0w + g * 16 + li) * 256 + quad * 8];

    f32x4 oa[2][2];
#pragma unroll
    for (int g = 0; g < 2; g++)
#pragma unroll
        for (int hf = 0; hf < 2; hf++) oa[g][hf] = (f32x4){0.f, 0.f, 0.f, 0.f};
    float lr[2] = {0.f, 0.f};
    const f32x4 zero = (f32x4){0.f, 0.f, 0.f, 0.f};

    // cooperative staging addresses (256 threads cover 4KB K + 4KB V per tile)
    int krow = tid >> 2, kcol = (tid & 3) << 3;   // K: 64 rows x 32d
    int vrow = tid >> 3, vcol = (tid & 7) << 3;   // V: 32 rows x 64m
    const short* kgp = KP + (size_t)krow * HD_ + kcol;   // fully sequential stream
    const short* vgp = V + (size_t)vrow * N_ + vcol;     // 128B per row
    int klo = krow * 40 + kcol;
    int vlo = vrow * 72 + vcol;

    short8 kst = *(const short8*)kgp;
    short8 vst = *(const short8*)vgp;

    for (int mt = 0; mt < 64; mt++) {
        int buf = mt & 1;
        *(short8*)&kl[buf][klo] = kst;
        *(short8*)&vl[buf][vlo] = vst;
        __syncthreads();
        if (mt < 63) {   // global prefetch of next tile overlaps compute
            kst = *(const short8*)(kgp + (size_t)(mt + 1) * 64 * HD_);
            vst = *(const short8*)(vgp + (mt + 1) * 64);
        }

        // S^T = K * Q^T: lane holds rows m=c*16+quad*4+r, col n=li
        f32x4 s[2][4];
#pragma unroll
        for (int c = 0; c < 4; c++) {
            short8 kf = *(short8*)&kl[buf][(c * 16 + li) * 40 + quad * 8];
            s[0][c] = __builtin_amdgcn_mfma_f32_16x16x32_bf16(kf, qf[0], zero, 0, 0, 0);
            s[1][c] = __builtin_amdgcn_mfma_f32_16x16x32_bf16(kf, qf[1], zero, 0, 0, 0);
        }

        // exp2 (no max), pack to bf16 P^T in LDS, accumulate denominator
#pragma unroll
        for (int g = 0; g < 2; g++) {
            short* plw = plw_base + g * (16 * 72);
            float lp = 0.f;
#pragma unroll
            for (int c = 0; c < 4; c++) {
                float e0 = __builtin_amdgcn_exp2f(s[g][c][0]);
                float e1 = __builtin_amdgcn_exp2f(s[g][c][1]);
                float e2 = __builtin_amdgcn_exp2f(s[g][c][2]);
                float e3 = __builtin_amdgcn_exp2f(s[g][c][3]);
                lp += (e0 + e1) + (e2 + e3);
                unsigned pk0 = __builtin_amdgcn_perm(__float_as_uint(e1), __float_as_uint(e0), 0x07060302);
                unsigned pk1 = __builtin_amdgcn_perm(__float_as_uint(e3), __float_as_uint(e2), 0x07060302);
                uint2 pkv; pkv.x = pk0; pkv.y = pk1;
                *(uint2*)&plw[li * 72 + c * 16 + quad * 4] = pkv;
            }
            lr[g] += lp;
        }

        // O += P * V: V-frags read once, shared across g
        short8 vf00 = *(short8*)&vl[buf][li * 72 + quad * 8];
        short8 vf01 = *(short8*)&vl[buf][(16 + li) * 72 + quad * 8];
        short8 vf10 = *(short8*)&vl[buf][li * 72 + 32 + quad * 8];
        short8 vf11 = *(short8*)&vl[buf][(16 + li) * 72 + 32 + quad * 8];
#pragma unroll
        for (int g = 0; g < 2; g++) {
            short* plw = plw_base + g * (16 * 72);
            short8 pf0 = *(short8*)&plw[li * 72 + quad * 8];
            short8 pf1 = *(short8*)&plw[li * 72 + 32 + quad * 8];
            oa[g][0] = __builtin_amdgcn_mfma_f32_16x16x32_bf16(pf0, vf00, oa[g][0], 0, 0, 0);
            oa[g][1] = __builtin_amdgcn_mfma_f32_16x16x32_bf16(pf0, vf01, oa[g][1], 0, 0, 0);
            oa[g][0] = __builtin_amdgcn_mfma_f32_16x16x32_bf16(pf1, vf10, oa[g][0], 0, 0, 0);
            oa[g][1] = __builtin_amdgcn_mfma_f32_16x16x32_bf16(pf1, vf11, oa[g][1], 0, 0, 0);
        }
    }

    // denominator: combine 4 quads (same li = same n); per-wave O write (disjoint n)
#pragma unroll
    for (int g = 0; g < 2; g++) {
        lr[g] += __shfl_xor(lr[g], 16);
        lr[g] += __shfl_xor(lr[g], 32);
    }
#pragma unroll
    for (int g = 0; g < 2; g++)
#pragma unroll
        for (int r2 = 0; r2 < 4; r2++) {
            float ln = __shfl(lr[g], quad * 4 + r2);
            float inv = 1.f / ln;
            size_t n_ = (size_t)(n0w + g * 16 + quad * 4 + r2);
            O[n_ * 256 + li]      = f2b(oa[g][0][r2] * inv);
            O[n_ * 256 + 16 + li] = f2b(oa[g][1][r2] * inv);
        }
}

// ---------------- Out projection + bias + residual -> d_out (f32) ----------------
__global__ __launch_bounds__(256) void gemm_out(const float* __restrict__ W,
                                                const float* __restrict__ bias,
                                                const short* __restrict__ aoT,
                                                const float* __restrict__ resid,
                                                float* __restrict__ out) {
    int b = blockIdx.z;
    const short* X = aoT + (size_t)b * N_ * C_;
    const float* R = resid + (size_t)b * C_ * N_;
    float* outp = out + (size_t)b * C_ * N_;

    __shared__ short wl[128][40];
    __shared__ short xl[128][40];

    int o0 = blockIdx.y * 128, n0 = blockIdx.x * 128;
    int tid = threadIdx.x;
    int w = tid >> 6, lane = tid & 63, li = lane & 15, quad = lane >> 4;
    int wr = w >> 1, wc = w & 1;

    f32x4 acc[4][4];
#pragma unroll
    for (int i = 0; i < 4; i++)
#pragma unroll
        for (int j = 0; j < 4; j++) acc[i][j] = (f32x4){0.f, 0.f, 0.f, 0.f};

    for (int k0 = 0; k0 < 256; k0 += 32) {
#pragma unroll
        for (int i = 0; i < 2; i++) {
            int idx = tid + i * 256;
            int row = idx >> 2, co = (idx & 3) << 3;
            const float* wp = &W[(size_t)(o0 + row) * 256 + k0 + co];
            f4 wa = *(const f4*)wp;
            f4 wb = *(const f4*)(wp + 4);
            short8 w8;
#pragma unroll
            for (int j = 0; j < 4; j++) { w8[j] = f2b(wa[j]); w8[j + 4] = f2b(wb[j]); }
            *(short8*)&wl[row][co] = w8;
            *(short8*)&xl[row][co] = *(const short8*)&X[(size_t)(n0 + row) * 256 + k0 + co];
        }
        __syncthreads();
        short8 af[4], bfr[4];
#pragma unroll
        for (int i = 0; i < 4; i++) af[i]  = *(short8*)&wl[wr * 64 + i * 16 + li][quad * 8];
#pragma unroll
        for (int j = 0; j < 4; j++) bfr[j] = *(short8*)&xl[wc * 64 + j * 16 + li][quad * 8];
#pragma unroll
        for (int i = 0; i < 4; i++)
#pragma unroll
            for (int j = 0; j < 4; j++)
                acc[i][j] = __builtin_amdgcn_mfma_f32_16x16x32_bf16(af[i], bfr[j], acc[i][j], 0, 0, 0);
        __syncthreads();
    }
#pragma unroll
    for (int i = 0; i < 4; i++) {
        int ob = o0 + wr * 64 + i * 16 + quad * 4;
#pragma unroll
        for (int j = 0; j < 4; j++) {
            int n_ = n0 + wc * 64 + j * 16 + li;
#pragma unroll
            for (int r = 0; r < 4; r++) {
                size_t idx = (size_t)(ob + r) * N_ + n_;
                outp[idx] = acc[i][j][r] + bias[ob + r] + R[idx];
            }
        }
    }
}

extern "C" void kernel_launch(void* const* d_in, const int* in_sizes, int n_in,
                              void* d_out, int out_size, void* d_ws, size_t ws_size,
                              hipStream_t stream) {
    const float* x  = (const float*)d_in[0];
    const float* gw = (const float*)d_in[1];
    const float* gb = (const float*)d_in[2];
    const float* wq = (const float*)d_in[3];
    const float* bq = (const float*)d_in[4];
    const float* wk = (const float*)d_in[5];
    const float* bk = (const float*)d_in[6];
    const float* wv = (const float*)d_in[7];
    const float* bv = (const float*)d_in[8];
    const float* wo = (const float*)d_in[9];
    const float* bo = (const float*)d_in[10];
    float* out = (float*)d_out;

    char* ws = (char*)d_ws;
    float* part = (float*)ws;             // 2048 floats
    const size_t TS = (size_t)B_ * N_ * C_;  // 2M elements per bf16 tensor
    short* xnT = (short*)(ws + 16384);
    short* q   = xnT + TS;
    short* kt  = q + TS;    // packed [b*8+h][m][32]
    short* v   = kt + TS;
    short* aoT = xnT;  // alias: xnT dead after gemm_qkv

    gn_part<<<1024, 256, 0, stream>>>(x, part);
    gn_apply<<<1024, 256, 0, stream>>>(x, gw, gb, part, xnT);
    gemm_qkv<<<dim3(32, 2, 6), 256, 0, stream>>>(wq, wk, wv, bq, bk, bv, xnT, q, kt, v);
    flash<<<512, 256, 0, stream>>>(q, kt, v, aoT);
    gemm_out<<<dim3(32, 2, 2), 256, 0, stream>>>(wo, bo, aoT, x, out);
}